// Round 9
// baseline (16.732 us; speedup 1.0000x reference)
//
#include <hip/hip_runtime.h>

// 3D neighborhood attention, 40^3, NH=8, HD=6, KS=3 (27 neighbors).
// Block = 4x4x8 voxel tile x 4 head-pairs, 256 thr; thread owns a z-PAIR of
// voxels -> per (i,j) reads the 4-row z-union once (18+18 LDS reads/voxel
// instead of 27+27), rpb shared. Halo 6x6x10 staged as packed f16 by
// voxel-ownership (2 voxels/thread, coords computed once, contiguous f4).
// LDS col strides 44/22 dw -> uniform bank-start spread for b128 reads.
// exp2 with log2e folded into q-scale and rpb. Paired float2 output stores.

#define GS    40
#define NVOX  (GS*GS*GS)
#define C4    44            // k4 column stride (10 rows + 1 pad, uint4) in dw
#define S4    1608          // k4 hp stride in dw (36*44 + 24), ==8 mod 32
#define C2    22            // k2 column stride in dw
#define S2    792           // k2 hp stride in dw, ==24 mod 32
#define S2OFF (4*S4)        // 6432 dw

typedef __fp16 half2_t __attribute__((ext_vector_type(2)));
typedef float  f2      __attribute__((ext_vector_type(2)));

__device__ __forceinline__ float fdot2(half2_t a, half2_t b, float c) {
    return __builtin_amdgcn_fdot2(a, b, c, false);
}
__device__ __forceinline__ half2_t h2(unsigned int u) {
    return __builtin_bit_cast(half2_t, u);
}
__device__ __forceinline__ unsigned int pk(float a, float b) {
    return __builtin_bit_cast(unsigned int, __builtin_amdgcn_cvt_pkrtz(a, b));
}

__global__ __launch_bounds__(256) void natt_kernel(
    const float* __restrict__ q, const float* __restrict__ kk,
    const float* __restrict__ rpb, float* __restrict__ out)
{
    __shared__ __align__(16) unsigned int sk[S2OFF + 4 * S2];  // 38.4 KB
    __shared__ float srpb[4 * 27 * 2];

    int t = threadIdx.x;
    int b = blockIdx.x;
    // bijective XCD swizzle for 500 blocks: q=62, r=4
    int xcd = b & 7, off = b >> 3;
    int w = (xcd < 4 ? xcd * 63 : 252 + (xcd - 4) * 62) + off;
    int bz = w % 5, byx = w / 5;
    int by = byx % 10, bx = byx / 10;
    int x0 = bx * 4, y0 = by * 4, z0 = bz * 8;

    if (t < 216) {
        int h = t / 27, n = t % 27;
        srpb[((h >> 1) * 27 + n) * 2 + (h & 1)] = rpb[t] * 1.4426950408889634f;
    }

    // ---- stage 6x6x10 halo as packed f16, 2 voxels per thread (t<180) ----
    const float4* kk4 = (const float4*)kk;
    if (t < 180) {
        #pragma unroll
        for (int svi = 0; svi < 2; ++svi) {
            int vv  = 2 * t + svi;          // halo voxel 0..359
            int col = vv / 10;              // hx*6+hy
            int hz  = vv - col * 10;
            int hx  = col / 6, hy = col - hx * 6;
            int gx = x0 + hx - 1, gy = y0 + hy - 1, gz = z0 + hz - 1;
            bool valid = ((unsigned)gx < GS) & ((unsigned)gy < GS) & ((unsigned)gz < GS);
            const float4* src = kk4 + (size_t)(gx * 1600 + gy * 40 + gz) * 12;
            #pragma unroll
            for (int hp_c = 0; hp_c < 4; ++hp_c) {
                float4 f0, f1, f2v;
                if (valid) {
                    f0 = src[hp_c * 3 + 0]; f1 = src[hp_c * 3 + 1]; f2v = src[hp_c * 3 + 2];
                } else {
                    f0 = f1 = f2v = make_float4(0.f, 0.f, 0.f, 0.f);
                }
                uint4 u4v;
                u4v.x = pk(f0.x, f0.y); u4v.y = pk(f0.z, f0.w);
                u4v.z = pk(f1.x, f1.y); u4v.w = pk(f1.z, f1.w);
                uint2 u2v;
                u2v.x = pk(f2v.x, f2v.y); u2v.y = pk(f2v.z, f2v.w);
                *(uint4*)(sk + hp_c * S4 + col * C4 + hz * 4) = u4v;
                *(uint2*)(sk + S2OFF + hp_c * S2 + col * C2 + hz * 2) = u2v;
            }
        }
    }

    // ---- q for the two voxels of this thread (overlaps staging) ----
    int hp = t & 3;
    int vp = t >> 2;
    int vzp = vp & 3, vy = (vp >> 2) & 3, vx = vp >> 4;
    int gvoxA = (x0 + vx) * 1600 + (y0 + vy) * 40 + (z0 + 2 * vzp);
    const float4* qpA = (const float4*)q + (size_t)gvoxA * 12 + hp * 3;
    float4 a0 = qpA[0], a1 = qpA[1], a2 = qpA[2];
    float4 b0 = qpA[12], b1 = qpA[13], b2 = qpA[14];

    const float QS = 0.4082482904638631f * 1.4426950408889634f;
    half2_t qA0 = __builtin_amdgcn_cvt_pkrtz(a0.x*QS, a0.y*QS);
    half2_t qA1 = __builtin_amdgcn_cvt_pkrtz(a0.z*QS, a0.w*QS);
    half2_t qA2 = __builtin_amdgcn_cvt_pkrtz(a1.x*QS, a1.y*QS);
    half2_t qA3 = __builtin_amdgcn_cvt_pkrtz(a1.z*QS, a1.w*QS);
    half2_t qA4 = __builtin_amdgcn_cvt_pkrtz(a2.x*QS, a2.y*QS);
    half2_t qA5 = __builtin_amdgcn_cvt_pkrtz(a2.z*QS, a2.w*QS);
    half2_t qB0 = __builtin_amdgcn_cvt_pkrtz(b0.x*QS, b0.y*QS);
    half2_t qB1 = __builtin_amdgcn_cvt_pkrtz(b0.z*QS, b0.w*QS);
    half2_t qB2 = __builtin_amdgcn_cvt_pkrtz(b1.x*QS, b1.y*QS);
    half2_t qB3 = __builtin_amdgcn_cvt_pkrtz(b1.z*QS, b1.w*QS);
    half2_t qB4 = __builtin_amdgcn_cvt_pkrtz(b2.x*QS, b2.y*QS);
    half2_t qB5 = __builtin_amdgcn_cvt_pkrtz(b2.z*QS, b2.w*QS);

    __syncthreads();

    const f2* rp2 = (const f2*)srpb + hp * 27;

    f2 denA = {0,0}, ozA = {0,0}, xpA = {0,0}, xmA = {0,0}, ypA = {0,0}, ymA = {0,0};
    f2 denB = {0,0}, ozB = {0,0}, xpB = {0,0}, xmB = {0,0}, ypB = {0,0}, ymB = {0,0};

    #pragma unroll
    for (int i = 0; i < 3; ++i)
    #pragma unroll
    for (int j = 0; j < 3; ++j) {
        int col = (vx + i) * 6 + (vy + j);
        const unsigned int* p4 = sk + hp * S4 + col * C4 + (2 * vzp) * 4;
        const unsigned int* p2 = sk + S2OFF + hp * S2 + col * C2 + (2 * vzp) * 2;
        uint4 R4[4]; uint2 R2[4];
        #pragma unroll
        for (int r = 0; r < 4; ++r) {
            R4[r] = *(const uint4*)(p4 + r * 4);
            R2[r] = *(const uint2*)(p2 + r * 2);
        }
        f2 eA[3], eB[3];
        #pragma unroll
        for (int l = 0; l < 3; ++l) {
            f2 rp = rp2[i * 9 + j * 3 + l];
            float dA0 = fdot2(qA0, h2(R4[l].x),
                        fdot2(qA1, h2(R4[l].y),
                        fdot2(qA2, h2(R4[l].z), rp.x)));
            float dA1 = fdot2(qA3, h2(R4[l].w),
                        fdot2(qA4, h2(R2[l].x),
                        fdot2(qA5, h2(R2[l].y), rp.y)));
            float dB0 = fdot2(qB0, h2(R4[l+1].x),
                        fdot2(qB1, h2(R4[l+1].y),
                        fdot2(qB2, h2(R4[l+1].z), rp.x)));
            float dB1 = fdot2(qB3, h2(R4[l+1].w),
                        fdot2(qB4, h2(R2[l+1].x),
                        fdot2(qB5, h2(R2[l+1].y), rp.y)));
            eA[l].x = __builtin_amdgcn_exp2f(dA0);
            eA[l].y = __builtin_amdgcn_exp2f(dA1);
            eB[l].x = __builtin_amdgcn_exp2f(dB0);
            eB[l].y = __builtin_amdgcn_exp2f(dB1);
        }
        f2 A = eA[0] + eA[1] + eA[2];
        f2 B = eB[0] + eB[1] + eB[2];
        denA += A; denB += B;
        ozA += eA[2] - eA[0]; ozB += eB[2] - eB[0];
        if (i == 0)      { xmA += A; xmB += B; }
        else if (i == 2) { xpA += A; xpB += B; }
        if (j == 0)      { ymA += A; ymB += B; }
        else if (j == 2) { ypA += A; ypB += B; }
    }

    f2 oxA = xpA - xmA, oyA = ypA - ymA;
    f2 oxB = xpB - xmB, oyB = ypB - ymB;
    float iA0 = __builtin_amdgcn_rcpf(denA.x);
    float iA1 = __builtin_amdgcn_rcpf(denA.y);
    float iB0 = __builtin_amdgcn_rcpf(denB.x);
    float iB1 = __builtin_amdgcn_rcpf(denB.y);

    float* op = out + (size_t)(hp * 6) * NVOX + gvoxA;
    f2 s0 = {oxA.x * iA0, oxB.x * iB0}; *(f2*)(op + 0*NVOX) = s0;
    f2 s1 = {oyA.x * iA0, oyB.x * iB0}; *(f2*)(op + 1*NVOX) = s1;
    f2 s2 = {ozA.x * iA0, ozB.x * iB0}; *(f2*)(op + 2*NVOX) = s2;
    f2 s3 = {oxA.y * iA1, oxB.y * iB1}; *(f2*)(op + 3*NVOX) = s3;
    f2 s4 = {oyA.y * iA1, oyB.y * iB1}; *(f2*)(op + 4*NVOX) = s4;
    f2 s5 = {ozA.y * iA1, ozB.y * iB1}; *(f2*)(op + 5*NVOX) = s5;
}

extern "C" void kernel_launch(void* const* d_in, const int* in_sizes, int n_in,
                              void* d_out, int out_size, void* d_ws, size_t ws_size,
                              hipStream_t stream) {
    const float* q   = (const float*)d_in[0];
    const float* k   = (const float*)d_in[1];
    const float* rpb = (const float*)d_in[2];
    float* out = (float*)d_out;

    natt_kernel<<<500, 256, 0, stream>>>(q, k, rpb, out);
}

// Round 10
// 14.452 us; speedup vs baseline: 1.1578x; 1.1578x over previous
//
#include <hip/hip_runtime.h>

// 3D neighborhood attention, 40^3, NH=8, HD=6, KS=3 (27 neighbors).
// Block = 4x4x4 voxel tile x 4 head-pairs (256 thr), grid 1000 (4000 waves).
// 6x6x6 k-halo in LDS as packed f16, single region: 36 dw/voxel, hp slot = 8 dw
// (dims0-7 @ +0..3 b128, dims8-11 @ +4..5 b64, +6..7 pad) -> all 27 reads are
// ONE base reg + compile-time immediates; 8 uniform bank starts.
// Staging: division-free via vtab[224] (clamped gvox*12 | valid<<30), 7 iters,
// 8 slots/voxel, offset-folded, and-mask for OOB (zero-fill -> score=rpb).
// rpb grouped [hp][9][4 f2]: b128(l0,l1)+b64(l2). exp2 with log2e folded.

#define GS   40
#define NVOX (GS*GS*GS)
#define VST  36              // dwords per halo voxel in LDS

typedef __fp16 half2_t __attribute__((ext_vector_type(2)));
typedef float  f2      __attribute__((ext_vector_type(2)));

__device__ __forceinline__ float fdot2(half2_t a, half2_t b, float c) {
    return __builtin_amdgcn_fdot2(a, b, c, false);
}
__device__ __forceinline__ half2_t h2(unsigned int u) {
    return __builtin_bit_cast(half2_t, u);
}
__device__ __forceinline__ unsigned int pk(float a, float b) {
    return __builtin_bit_cast(unsigned int, __builtin_amdgcn_cvt_pkrtz(a, b));
}

__global__ __launch_bounds__(256) void natt_kernel(
    const float* __restrict__ q, const float* __restrict__ kk,
    const float* __restrict__ rpb, float* __restrict__ out)
{
    __shared__ __align__(16) unsigned int sk[224 * VST];  // 32.3 KB
    __shared__ float srpb[4 * 72];                        // [hp][9 grp][4 f2]
    __shared__ int   vtab[224];

    int t = threadIdx.x;
    int b = blockIdx.x;
    int w = (b & 7) * 125 + (b >> 3);   // XCD chunking (bijective: 1000=8*125)
    int bz = w % 10, by = (w / 10) % 10, bx = w / 100;
    int x0 = bx * 4, y0 = by * 4, z0 = bz * 4;

    // ---- q loads issued first (overlap everything) ----
    int hp = t & 3;
    int v  = t >> 2;
    int vz = v & 3, vy = (v >> 2) & 3, vx = v >> 4;
    int gvox = (x0 + vx) * 1600 + (y0 + vy) * 40 + (z0 + vz);
    const float4* qp = (const float4*)q + (size_t)gvox * 12 + hp * 3;
    float4 qa = qp[0], qb = qp[1], qc = qp[2];

    // ---- one-time tables ----
    if (t < 224) {
        int vvc = t < 216 ? t : 215;
        int xi = vvc / 36, r36 = vvc - xi * 36;
        int yi = r36 / 6,  zi  = r36 - yi * 6;
        int gx = x0 + xi - 1, gy = y0 + yi - 1, gz = z0 + zi - 1;
        bool val = (((unsigned)gx < GS) & ((unsigned)gy < GS) &
                    ((unsigned)gz < GS)) && (t < 216);
        int cx = min(max(gx, 0), GS - 1);
        int cy = min(max(gy, 0), GS - 1);
        int cz = min(max(gz, 0), GS - 1);
        vtab[t] = ((cx * 1600 + cy * 40 + cz) * 12) | (val ? (1 << 30) : 0);
    }
    if (t < 216) {
        int h = t / 27, n = t - h * 27;
        int i = n / 9, r9 = n - i * 9;
        int j = r9 / 3, l = r9 - j * 3;
        srpb[(h >> 1) * 72 + ((i * 3 + j) * 4 + l) * 2 + (h & 1)] =
            rpb[t] * 1.4426950408889634f;
    }
    __syncthreads();

    // ---- stage halo: 7 iters, 8 slots/voxel, division-free ----
    {
        const float4* kk4 = (const float4*)kk;
        int sub = t & 7;
        int hpc = sub >> 1, pt = sub & 1;
        int soffA = hpc * 3 + pt * 2;          // f4 index of first load
        int soffB = soffA + (pt ? 0 : 1);      // second (junk for pt1 -> pads)
        unsigned int* dstb = sk + (t >> 3) * VST + hpc * 8 + pt * 4;
        const int* vtp = vtab + (t >> 3);
        #pragma unroll
        for (int it = 0; it < 7; ++it) {
            int rec = vtp[it * 32];
            unsigned m = (unsigned)(((int)(rec << 1)) >> 31); // ~0 if valid
            int base = rec & 0x3FFFFFFF;
            float4 fA = kk4[base + soffA];
            float4 fB = kk4[base + soffB];
            uint4 u;
            u.x = pk(fA.x, fA.y) & m; u.y = pk(fA.z, fA.w) & m;
            u.z = pk(fB.x, fB.y) & m; u.w = pk(fB.z, fB.w) & m;
            *(uint4*)(dstb + it * 32 * VST) = u;
        }
    }

    // ---- pack q into 6 half2, pre-scaled by 6^-0.5 * log2(e) ----
    const float QS = 0.4082482904638631f * 1.4426950408889634f;
    half2_t qh0 = __builtin_amdgcn_cvt_pkrtz(qa.x*QS, qa.y*QS);
    half2_t qh1 = __builtin_amdgcn_cvt_pkrtz(qa.z*QS, qa.w*QS);
    half2_t qh2 = __builtin_amdgcn_cvt_pkrtz(qb.x*QS, qb.y*QS);
    half2_t qh3 = __builtin_amdgcn_cvt_pkrtz(qb.z*QS, qb.w*QS);
    half2_t qh4 = __builtin_amdgcn_cvt_pkrtz(qc.x*QS, qc.y*QS);
    half2_t qh5 = __builtin_amdgcn_cvt_pkrtz(qc.z*QS, qc.w*QS);

    __syncthreads();

    // ---- compute: one base reg, all 27 reads via compile-time immediates ----
    const unsigned int* kbp = sk + (vx * 36 + vy * 6 + vz) * VST + hp * 8;
    const float* rbp = srpb + hp * 72;

    f2 den = {0,0}, ozc = {0,0};
    f2 xp = {0,0}, xm = {0,0}, yp = {0,0}, ym = {0,0};

    #pragma unroll
    for (int i = 0; i < 3; ++i)
    #pragma unroll
    for (int j = 0; j < 3; ++j) {
        const unsigned int* cb = kbp + (i * 36 + j * 6) * VST;
        float4 rp01 = *(const float4*)(rbp + (i * 3 + j) * 8);
        f2     rp2v = *(const f2*)(rbp + (i * 3 + j) * 8 + 4);
        f2 ev[3];
        #pragma unroll
        for (int l = 0; l < 3; ++l) {
            uint4 a = *(const uint4*)(cb + l * VST);
            uint2 c = *(const uint2*)(cb + l * VST + 4);
            float rx = (l == 0) ? rp01.x : (l == 1) ? rp01.z : rp2v.x;
            float ry = (l == 0) ? rp01.y : (l == 1) ? rp01.w : rp2v.y;
            float d0 = fdot2(qh0, h2(a.x),
                       fdot2(qh1, h2(a.y),
                       fdot2(qh2, h2(a.z), rx)));
            float d1 = fdot2(qh3, h2(a.w),
                       fdot2(qh4, h2(c.x),
                       fdot2(qh5, h2(c.y), ry)));
            ev[l].x = __builtin_amdgcn_exp2f(d0);
            ev[l].y = __builtin_amdgcn_exp2f(d1);
        }
        f2 A = ev[0] + ev[1] + ev[2];
        den += A;
        ozc += ev[2] - ev[0];
        if (i == 0)      xm += A;
        else if (i == 2) xp += A;
        if (j == 0)      ym += A;
        else if (j == 2) yp += A;
    }

    f2 oxv = xp - xm, oyv = yp - ym;
    float inv0 = __builtin_amdgcn_rcpf(den.x);
    float inv1 = __builtin_amdgcn_rcpf(den.y);

    float* op = out + (size_t)(hp * 6) * NVOX + gvox;
    op[0*NVOX] = oxv.x * inv0;
    op[1*NVOX] = oyv.x * inv0;
    op[2*NVOX] = ozc.x * inv0;
    op[3*NVOX] = oxv.y * inv1;
    op[4*NVOX] = oyv.y * inv1;
    op[5*NVOX] = ozc.y * inv1;
}

extern "C" void kernel_launch(void* const* d_in, const int* in_sizes, int n_in,
                              void* d_out, int out_size, void* d_ws, size_t ws_size,
                              hipStream_t stream) {
    const float* q   = (const float*)d_in[0];
    const float* k   = (const float*)d_in[1];
    const float* rpb = (const float*)d_in[2];
    float* out = (float*)d_out;

    natt_kernel<<<1000, 256, 0, stream>>>(q, k, rpb, out);
}

// Round 11
// 13.976 us; speedup vs baseline: 1.1972x; 1.0341x over previous
//
#include <hip/hip_runtime.h>

// 3D neighborhood attention, 40^3, NH=8, HD=6, KS=3 (27 neighbors).
// Tile 8x4x4 voxels x 4 head-pairs, block 512, grid 500 (4000 waves).
// Halo 10x6x6=360 voxels (2.8 halo/output vs 3.4 for 4^3 tile) staged as
// packed f16, ONE whole voxel per thread (t<360): coords/clamp/valid once,
// no vtab, no per-f4 divides. Zero-fill OOB -> score = rpb semantics.
// LDS: 36 dw/voxel, hp slot 8 dw (b128 dims0-7 + b64 dims8-11 + 2 pad) ->
// all 27 k-reads from ONE base reg + compile-time immediates.
// exp2 with log2e folded into q-scale and rpb. Single barrier.

#define GS   40
#define NVOX (GS*GS*GS)
#define VST  36              // dwords per halo voxel in LDS

typedef __fp16 half2_t __attribute__((ext_vector_type(2)));
typedef float  f2      __attribute__((ext_vector_type(2)));

__device__ __forceinline__ float fdot2(half2_t a, half2_t b, float c) {
    return __builtin_amdgcn_fdot2(a, b, c, false);
}
__device__ __forceinline__ half2_t h2(unsigned int u) {
    return __builtin_bit_cast(half2_t, u);
}
__device__ __forceinline__ unsigned int pk(float a, float b) {
    return __builtin_bit_cast(unsigned int, __builtin_amdgcn_cvt_pkrtz(a, b));
}

__global__ __launch_bounds__(512, 4) void natt_kernel(
    const float* __restrict__ q, const float* __restrict__ kk,
    const float* __restrict__ rpb, float* __restrict__ out)
{
    __shared__ __align__(16) unsigned int sk[360 * VST];  // 51.8 KB
    __shared__ float srpb[4 * 72];                        // [hp][9 grp][4 f2]

    int t = threadIdx.x;
    int b = blockIdx.x;
    // bijective XCD swizzle for 500 blocks: q=62, r=4
    int xcd = b & 7, off = b >> 3;
    int w = (xcd < 4 ? xcd * 63 : 252 + (xcd - 4) * 62) + off;
    int bz = w % 10, by = (w / 10) % 10, bx = w / 100;   // bx 0..4
    int x0 = bx * 8, y0 = by * 4, z0 = bz * 4;

    // ---- q loads issued first (overlap staging) ----
    int hp = t & 3;
    int v  = t >> 2;                 // 0..127
    int vz = v & 3, vy = (v >> 2) & 3, vx = v >> 4;   // vx 0..7
    int gvox = (x0 + vx) * 1600 + (y0 + vy) * 40 + (z0 + vz);
    const float4* qp = (const float4*)q + (size_t)gvox * 12 + hp * 3;
    float4 qa = qp[0], qb = qp[1], qc = qp[2];

    if (t < 216) {
        int h = t / 27, n = t - h * 27;
        int i = n / 9, r9 = n - i * 9;
        int j = r9 / 3, l = r9 - j * 3;
        srpb[(h >> 1) * 72 + ((i * 3 + j) * 4 + l) * 2 + (h & 1)] =
            rpb[t] * 1.4426950408889634f;
    }

    // ---- stage halo: one whole voxel per thread (t<360) ----
    if (t < 360) {
        int hx = t / 36, r36 = t - hx * 36;
        int hy = r36 / 6, hz = r36 - hy * 6;
        int gx = x0 + hx - 1, gy = y0 + hy - 1, gz = z0 + hz - 1;
        unsigned m = (((unsigned)gx < GS) & ((unsigned)gy < GS) &
                      ((unsigned)gz < GS)) ? 0xffffffffu : 0u;
        int cx = min(max(gx, 0), GS - 1);
        int cy = min(max(gy, 0), GS - 1);
        int cz = min(max(gz, 0), GS - 1);
        const float4* src = (const float4*)kk +
                            (size_t)(cx * 1600 + cy * 40 + cz) * 12;
        unsigned int* dst = sk + t * VST;
        #pragma unroll
        for (int hpc = 0; hpc < 4; ++hpc) {
            float4 f0 = src[hpc * 3 + 0];
            float4 f1 = src[hpc * 3 + 1];
            float4 fv = src[hpc * 3 + 2];
            uint4 u4v;
            u4v.x = pk(f0.x, f0.y) & m; u4v.y = pk(f0.z, f0.w) & m;
            u4v.z = pk(f1.x, f1.y) & m; u4v.w = pk(f1.z, f1.w) & m;
            uint2 u2v;
            u2v.x = pk(fv.x, fv.y) & m; u2v.y = pk(fv.z, fv.w) & m;
            *(uint4*)(dst + hpc * 8)     = u4v;
            *(uint2*)(dst + hpc * 8 + 4) = u2v;
        }
    }

    // ---- pack q into 6 half2, pre-scaled by 6^-0.5 * log2(e) ----
    const float QS = 0.4082482904638631f * 1.4426950408889634f;
    half2_t qh0 = __builtin_amdgcn_cvt_pkrtz(qa.x*QS, qa.y*QS);
    half2_t qh1 = __builtin_amdgcn_cvt_pkrtz(qa.z*QS, qa.w*QS);
    half2_t qh2 = __builtin_amdgcn_cvt_pkrtz(qb.x*QS, qb.y*QS);
    half2_t qh3 = __builtin_amdgcn_cvt_pkrtz(qb.z*QS, qb.w*QS);
    half2_t qh4 = __builtin_amdgcn_cvt_pkrtz(qc.x*QS, qc.y*QS);
    half2_t qh5 = __builtin_amdgcn_cvt_pkrtz(qc.z*QS, qc.w*QS);

    __syncthreads();

    // ---- compute: one base reg, all 27 reads via compile-time immediates ----
    const unsigned int* kbp = sk + (vx * 36 + vy * 6 + vz) * VST + hp * 8;
    const float* rbp = srpb + hp * 72;

    f2 den = {0,0}, ozc = {0,0};
    f2 xp = {0,0}, xm = {0,0}, yp = {0,0}, ym = {0,0};

    #pragma unroll
    for (int i = 0; i < 3; ++i)
    #pragma unroll
    for (int j = 0; j < 3; ++j) {
        const unsigned int* cb = kbp + (i * 36 + j * 6) * VST;
        float4 rp01 = *(const float4*)(rbp + (i * 3 + j) * 8);
        f2     rp2v = *(const f2*)(rbp + (i * 3 + j) * 8 + 4);
        f2 ev[3];
        #pragma unroll
        for (int l = 0; l < 3; ++l) {
            uint4 a = *(const uint4*)(cb + l * VST);
            uint2 c = *(const uint2*)(cb + l * VST + 4);
            float rx = (l == 0) ? rp01.x : (l == 1) ? rp01.z : rp2v.x;
            float ry = (l == 0) ? rp01.y : (l == 1) ? rp01.w : rp2v.y;
            float d0 = fdot2(qh0, h2(a.x),
                       fdot2(qh1, h2(a.y),
                       fdot2(qh2, h2(a.z), rx)));
            float d1 = fdot2(qh3, h2(a.w),
                       fdot2(qh4, h2(c.x),
                       fdot2(qh5, h2(c.y), ry)));
            ev[l].x = __builtin_amdgcn_exp2f(d0);
            ev[l].y = __builtin_amdgcn_exp2f(d1);
        }
        f2 A = ev[0] + ev[1] + ev[2];
        den += A;
        ozc += ev[2] - ev[0];
        if (i == 0)      xm += A;
        else if (i == 2) xp += A;
        if (j == 0)      ym += A;
        else if (j == 2) yp += A;
    }

    f2 oxv = xp - xm, oyv = yp - ym;
    float inv0 = __builtin_amdgcn_rcpf(den.x);
    float inv1 = __builtin_amdgcn_rcpf(den.y);

    float* op = out + (size_t)(hp * 6) * NVOX + gvox;
    op[0*NVOX] = oxv.x * inv0;
    op[1*NVOX] = oyv.x * inv0;
    op[2*NVOX] = ozc.x * inv0;
    op[3*NVOX] = oxv.y * inv1;
    op[4*NVOX] = oyv.y * inv1;
    op[5*NVOX] = ozc.y * inv1;
}

extern "C" void kernel_launch(void* const* d_in, const int* in_sizes, int n_in,
                              void* d_out, int out_size, void* d_ws, size_t ws_size,
                              hipStream_t stream) {
    const float* q   = (const float*)d_in[0];
    const float* k   = (const float*)d_in[1];
    const float* rpb = (const float*)d_in[2];
    float* out = (float*)d_out;

    natt_kernel<<<500, 512, 0, stream>>>(q, k, rpb, out);
}

// Round 12
// 13.781 us; speedup vs baseline: 1.2141x; 1.0142x over previous
//
#include <hip/hip_runtime.h>

// 3D neighborhood attention, 40^3, NH=8, HD=6, KS=3 (27 neighbors).
// Tile 4x4x8 voxels (z=8!) x 4 head-pairs, block 512, grid 500.
// z=8 tile -> output z-runs of 8 floats (32B segments, half the partial-line
// write amplification of z=4) and 10-voxel z-contiguous halo staging reads.
// Halo 6x6x10=360 voxels staged as packed f16, one whole voxel per thread.
// LDS: 36 dw/voxel, hp slot 8 dw -> all 27 k-reads one base + immediates.
// exp2 with log2e folded into q-scale and rpb. Bucketed accumulation.

#define GS   40
#define NVOX (GS*GS*GS)
#define VST  36              // dwords per halo voxel in LDS

typedef __fp16 half2_t __attribute__((ext_vector_type(2)));
typedef float  f2      __attribute__((ext_vector_type(2)));

__device__ __forceinline__ float fdot2(half2_t a, half2_t b, float c) {
    return __builtin_amdgcn_fdot2(a, b, c, false);
}
__device__ __forceinline__ half2_t h2(unsigned int u) {
    return __builtin_bit_cast(half2_t, u);
}
__device__ __forceinline__ unsigned int pk(float a, float b) {
    return __builtin_bit_cast(unsigned int, __builtin_amdgcn_cvt_pkrtz(a, b));
}

__global__ __launch_bounds__(512, 4) void natt_kernel(
    const float* __restrict__ q, const float* __restrict__ kk,
    const float* __restrict__ rpb, float* __restrict__ out)
{
    __shared__ __align__(16) unsigned int sk[360 * VST];  // 51.8 KB
    __shared__ float srpb[4 * 72];                        // [hp][9 grp][4 f2]

    int t = threadIdx.x;
    int b = blockIdx.x;
    // bijective XCD swizzle for 500 blocks (q=62, r=4); consecutive w are
    // z-adjacent tiles -> same XCD: L2 merges shared out-lines + halo faces.
    int xcd = b & 7, off = b >> 3;
    int w = (xcd < 4 ? xcd * 63 : 252 + (xcd - 4) * 62) + off;
    int bz = w % 5, byx = w / 5;
    int by = byx % 10, bx = byx / 10;
    int x0 = bx * 4, y0 = by * 4, z0 = bz * 8;

    // ---- q loads issued first (overlap staging) ----
    int hp = t & 3;
    int v  = t >> 2;                  // 0..127
    int vz = v & 7, vy = (v >> 3) & 3, vx = v >> 5;   // z=8, y=4, x=4
    int gvox = (x0 + vx) * 1600 + (y0 + vy) * 40 + (z0 + vz);
    const float4* qp = (const float4*)q + (size_t)gvox * 12 + hp * 3;
    float4 qa = qp[0], qb = qp[1], qc = qp[2];

    if (t < 216) {
        int h = t / 27, n = t - h * 27;
        int i = n / 9, r9 = n - i * 9;
        int j = r9 / 3, l = r9 - j * 3;
        srpb[(h >> 1) * 72 + ((i * 3 + j) * 4 + l) * 2 + (h & 1)] =
            rpb[t] * 1.4426950408889634f;
    }

    // ---- stage halo: one whole voxel per thread (t<360), z-major ----
    if (t < 360) {
        int hx = t / 60, r60 = t - hx * 60;
        int hy = r60 / 10, hz = r60 - hy * 10;
        int gx = x0 + hx - 1, gy = y0 + hy - 1, gz = z0 + hz - 1;
        unsigned m = (((unsigned)gx < GS) & ((unsigned)gy < GS) &
                      ((unsigned)gz < GS)) ? 0xffffffffu : 0u;
        int cx = min(max(gx, 0), GS - 1);
        int cy = min(max(gy, 0), GS - 1);
        int cz = min(max(gz, 0), GS - 1);
        const float4* src = (const float4*)kk +
                            (size_t)(cx * 1600 + cy * 40 + cz) * 12;
        unsigned int* dst = sk + t * VST;
        #pragma unroll
        for (int hpc = 0; hpc < 4; ++hpc) {
            float4 f0 = src[hpc * 3 + 0];
            float4 f1 = src[hpc * 3 + 1];
            float4 fv = src[hpc * 3 + 2];
            uint4 u4v;
            u4v.x = pk(f0.x, f0.y) & m; u4v.y = pk(f0.z, f0.w) & m;
            u4v.z = pk(f1.x, f1.y) & m; u4v.w = pk(f1.z, f1.w) & m;
            uint2 u2v;
            u2v.x = pk(fv.x, fv.y) & m; u2v.y = pk(fv.z, fv.w) & m;
            *(uint4*)(dst + hpc * 8)     = u4v;
            *(uint2*)(dst + hpc * 8 + 4) = u2v;
        }
    }

    // ---- pack q into 6 half2, pre-scaled by 6^-0.5 * log2(e) ----
    const float QS = 0.4082482904638631f * 1.4426950408889634f;
    half2_t qh0 = __builtin_amdgcn_cvt_pkrtz(qa.x*QS, qa.y*QS);
    half2_t qh1 = __builtin_amdgcn_cvt_pkrtz(qa.z*QS, qa.w*QS);
    half2_t qh2 = __builtin_amdgcn_cvt_pkrtz(qb.x*QS, qb.y*QS);
    half2_t qh3 = __builtin_amdgcn_cvt_pkrtz(qb.z*QS, qb.w*QS);
    half2_t qh4 = __builtin_amdgcn_cvt_pkrtz(qc.x*QS, qc.y*QS);
    half2_t qh5 = __builtin_amdgcn_cvt_pkrtz(qc.z*QS, qc.w*QS);

    __syncthreads();

    // ---- compute: one base reg, all 27 reads via compile-time immediates ----
    const unsigned int* kbp = sk + ((vx * 6 + vy) * 10 + vz) * VST + hp * 8;
    const float* rbp = srpb + hp * 72;

    f2 ozc = {0,0};
    f2 xb0 = {0,0}, xb1 = {0,0}, xb2 = {0,0};
    f2 yb0 = {0,0}, yb1 = {0,0}, yb2 = {0,0};

    #pragma unroll
    for (int i = 0; i < 3; ++i)
    #pragma unroll
    for (int j = 0; j < 3; ++j) {
        const unsigned int* cb = kbp + (i * 60 + j * 10) * VST;
        float4 rp01 = *(const float4*)(rbp + (i * 3 + j) * 8);
        f2     rp2v = *(const f2*)(rbp + (i * 3 + j) * 8 + 4);
        f2 ev[3];
        #pragma unroll
        for (int l = 0; l < 3; ++l) {
            uint4 a = *(const uint4*)(cb + l * VST);
            uint2 c = *(const uint2*)(cb + l * VST + 4);
            float rx = (l == 0) ? rp01.x : (l == 1) ? rp01.z : rp2v.x;
            float ry = (l == 0) ? rp01.y : (l == 1) ? rp01.w : rp2v.y;
            float d0 = fdot2(qh0, h2(a.x),
                       fdot2(qh1, h2(a.y),
                       fdot2(qh2, h2(a.z), rx)));
            float d1 = fdot2(qh3, h2(a.w),
                       fdot2(qh4, h2(c.x),
                       fdot2(qh5, h2(c.y), ry)));
            ev[l].x = __builtin_amdgcn_exp2f(d0);
            ev[l].y = __builtin_amdgcn_exp2f(d1);
        }
        f2 A = ev[0] + ev[1] + ev[2];
        ozc += ev[2] - ev[0];
        if (i == 0)      xb0 += A;
        else if (i == 1) xb1 += A;
        else             xb2 += A;
        if (j == 0)      yb0 += A;
        else if (j == 1) yb1 += A;
        else             yb2 += A;
    }

    f2 den = xb0 + xb1 + xb2;
    f2 oxv = xb2 - xb0, oyv = yb2 - yb0;
    float inv0 = __builtin_amdgcn_rcpf(den.x);
    float inv1 = __builtin_amdgcn_rcpf(den.y);

    float* op = out + (size_t)(hp * 6) * NVOX + gvox;
    op[0*NVOX] = oxv.x * inv0;
    op[1*NVOX] = oyv.x * inv0;
    op[2*NVOX] = ozc.x * inv0;
    op[3*NVOX] = oxv.y * inv1;
    op[4*NVOX] = oyv.y * inv1;
    op[5*NVOX] = ozc.y * inv1;
}

extern "C" void kernel_launch(void* const* d_in, const int* in_sizes, int n_in,
                              void* d_out, int out_size, void* d_ws, size_t ws_size,
                              hipStream_t stream) {
    const float* q   = (const float*)d_in[0];
    const float* k   = (const float*)d_in[1];
    const float* rpb = (const float*)d_in[2];
    float* out = (float*)d_out;

    natt_kernel<<<500, 512, 0, stream>>>(q, k, rpb, out);
}

// Round 13
// 13.320 us; speedup vs baseline: 1.2561x; 1.0346x over previous
//
#include <hip/hip_runtime.h>

// 3D neighborhood attention, 40^3, NH=8, HD=6, KS=3 (27 neighbors).
// Tile 4x4x8 voxels x 4 head-pairs, block 512, grid 500.
// Halo 6x6x10=360 voxels staged as packed f16, one whole voxel per thread;
// INTERIOR blocks (38%) take a clamp/mask-free staging fast path.
// LDS: 36 dw/voxel, hp slot 8 dw -> all 27 k-reads one base + immediates.
// s_setprio(1) around compute loop: compute-phase waves win issue slots over
// staging-phase waves of the co-resident block (T5 regime).
// exp2 with log2e folded into q-scale and rpb. Bucketed accumulation.

#define GS   40
#define NVOX (GS*GS*GS)
#define VST  36              // dwords per halo voxel in LDS

typedef __fp16 half2_t __attribute__((ext_vector_type(2)));
typedef float  f2      __attribute__((ext_vector_type(2)));

__device__ __forceinline__ float fdot2(half2_t a, half2_t b, float c) {
    return __builtin_amdgcn_fdot2(a, b, c, false);
}
__device__ __forceinline__ half2_t h2(unsigned int u) {
    return __builtin_bit_cast(half2_t, u);
}
__device__ __forceinline__ unsigned int pk(float a, float b) {
    return __builtin_bit_cast(unsigned int, __builtin_amdgcn_cvt_pkrtz(a, b));
}

__global__ __launch_bounds__(512, 4) void natt_kernel(
    const float* __restrict__ q, const float* __restrict__ kk,
    const float* __restrict__ rpb, float* __restrict__ out)
{
    __shared__ __align__(16) unsigned int sk[360 * VST];  // 51.8 KB
    __shared__ float srpb[4 * 72];                        // [hp][9 grp][4 f2]

    int t = threadIdx.x;
    int b = blockIdx.x;
    // bijective XCD swizzle for 500 blocks (q=62, r=4); consecutive w are
    // z-adjacent tiles -> same XCD: L2 merges shared out-lines + halo faces.
    int xcd = b & 7, off = b >> 3;
    int w = (xcd < 4 ? xcd * 63 : 252 + (xcd - 4) * 62) + off;
    int bz = w % 5, byx = w / 5;
    int by = byx % 10, bx = byx / 10;
    int x0 = bx * 4, y0 = by * 4, z0 = bz * 8;

    // ---- q loads issued first (overlap staging) ----
    int hp = t & 3;
    int v  = t >> 2;                  // 0..127
    int vz = v & 7, vy = (v >> 3) & 3, vx = v >> 5;   // z=8, y=4, x=4
    int gvox = (x0 + vx) * 1600 + (y0 + vy) * 40 + (z0 + vz);
    const float4* qp = (const float4*)q + (size_t)gvox * 12 + hp * 3;
    float4 qa = qp[0], qb = qp[1], qc = qp[2];

    if (t < 216) {
        int h = t / 27, n = t - h * 27;
        int i = n / 9, r9 = n - i * 9;
        int j = r9 / 3, l = r9 - j * 3;
        srpb[(h >> 1) * 72 + ((i * 3 + j) * 4 + l) * 2 + (h & 1)] =
            rpb[t] * 1.4426950408889634f;
    }

    // ---- stage halo: one whole voxel per thread (t<360), z-major ----
    // interior = entire halo in-bounds (block-uniform): no clamps, no masks.
    bool interior = (x0 >= 1) & (x0 <= 35) & (y0 >= 1) & (y0 <= 35) &
                    (z0 >= 1) & (z0 <= 31);
    if (t < 360) {
        int hx = t / 60, r60 = t - hx * 60;
        int hy = r60 / 10, hz = r60 - hy * 10;
        int gx = x0 + hx - 1, gy = y0 + hy - 1, gz = z0 + hz - 1;
        unsigned int* dst = sk + t * VST;
        if (interior) {
            const float4* src = (const float4*)kk +
                                (size_t)(gx * 1600 + gy * 40 + gz) * 12;
            #pragma unroll
            for (int hpc = 0; hpc < 4; ++hpc) {
                float4 f0 = src[hpc * 3 + 0];
                float4 f1 = src[hpc * 3 + 1];
                float4 fv = src[hpc * 3 + 2];
                uint4 u4v;
                u4v.x = pk(f0.x, f0.y); u4v.y = pk(f0.z, f0.w);
                u4v.z = pk(f1.x, f1.y); u4v.w = pk(f1.z, f1.w);
                uint2 u2v;
                u2v.x = pk(fv.x, fv.y); u2v.y = pk(fv.z, fv.w);
                *(uint4*)(dst + hpc * 8)     = u4v;
                *(uint2*)(dst + hpc * 8 + 4) = u2v;
            }
        } else {
            unsigned m = (((unsigned)gx < GS) & ((unsigned)gy < GS) &
                          ((unsigned)gz < GS)) ? 0xffffffffu : 0u;
            int cx = min(max(gx, 0), GS - 1);
            int cy = min(max(gy, 0), GS - 1);
            int cz = min(max(gz, 0), GS - 1);
            const float4* src = (const float4*)kk +
                                (size_t)(cx * 1600 + cy * 40 + cz) * 12;
            #pragma unroll
            for (int hpc = 0; hpc < 4; ++hpc) {
                float4 f0 = src[hpc * 3 + 0];
                float4 f1 = src[hpc * 3 + 1];
                float4 fv = src[hpc * 3 + 2];
                uint4 u4v;
                u4v.x = pk(f0.x, f0.y) & m; u4v.y = pk(f0.z, f0.w) & m;
                u4v.z = pk(f1.x, f1.y) & m; u4v.w = pk(f1.z, f1.w) & m;
                uint2 u2v;
                u2v.x = pk(fv.x, fv.y) & m; u2v.y = pk(fv.z, fv.w) & m;
                *(uint4*)(dst + hpc * 8)     = u4v;
                *(uint2*)(dst + hpc * 8 + 4) = u2v;
            }
        }
    }

    // ---- pack q into 6 half2, pre-scaled by 6^-0.5 * log2(e) ----
    const float QS = 0.4082482904638631f * 1.4426950408889634f;
    half2_t qh0 = __builtin_amdgcn_cvt_pkrtz(qa.x*QS, qa.y*QS);
    half2_t qh1 = __builtin_amdgcn_cvt_pkrtz(qa.z*QS, qa.w*QS);
    half2_t qh2 = __builtin_amdgcn_cvt_pkrtz(qb.x*QS, qb.y*QS);
    half2_t qh3 = __builtin_amdgcn_cvt_pkrtz(qb.z*QS, qb.w*QS);
    half2_t qh4 = __builtin_amdgcn_cvt_pkrtz(qc.x*QS, qc.y*QS);
    half2_t qh5 = __builtin_amdgcn_cvt_pkrtz(qc.z*QS, qc.w*QS);

    __syncthreads();

    // ---- compute: one base reg, all 27 reads via compile-time immediates ----
    __builtin_amdgcn_s_setprio(1);
    const unsigned int* kbp = sk + ((vx * 6 + vy) * 10 + vz) * VST + hp * 8;
    const float* rbp = srpb + hp * 72;

    f2 ozc = {0,0};
    f2 xb0 = {0,0}, xb1 = {0,0}, xb2 = {0,0};
    f2 yb0 = {0,0}, yb1 = {0,0}, yb2 = {0,0};

    #pragma unroll
    for (int i = 0; i < 3; ++i)
    #pragma unroll
    for (int j = 0; j < 3; ++j) {
        const unsigned int* cb = kbp + (i * 60 + j * 10) * VST;
        float4 rp01 = *(const float4*)(rbp + (i * 3 + j) * 8);
        f2     rp2v = *(const f2*)(rbp + (i * 3 + j) * 8 + 4);
        f2 ev[3];
        #pragma unroll
        for (int l = 0; l < 3; ++l) {
            uint4 a = *(const uint4*)(cb + l * VST);
            uint2 c = *(const uint2*)(cb + l * VST + 4);
            float rx = (l == 0) ? rp01.x : (l == 1) ? rp01.z : rp2v.x;
            float ry = (l == 0) ? rp01.y : (l == 1) ? rp01.w : rp2v.y;
            float d0 = fdot2(qh0, h2(a.x),
                       fdot2(qh1, h2(a.y),
                       fdot2(qh2, h2(a.z), rx)));
            float d1 = fdot2(qh3, h2(a.w),
                       fdot2(qh4, h2(c.x),
                       fdot2(qh5, h2(c.y), ry)));
            ev[l].x = __builtin_amdgcn_exp2f(d0);
            ev[l].y = __builtin_amdgcn_exp2f(d1);
        }
        f2 A = ev[0] + ev[1] + ev[2];
        ozc += ev[2] - ev[0];
        if (i == 0)      xb0 += A;
        else if (i == 1) xb1 += A;
        else             xb2 += A;
        if (j == 0)      yb0 += A;
        else if (j == 1) yb1 += A;
        else             yb2 += A;
    }
    __builtin_amdgcn_s_setprio(0);

    f2 den = xb0 + xb1 + xb2;
    f2 oxv = xb2 - xb0, oyv = yb2 - yb0;
    float inv0 = __builtin_amdgcn_rcpf(den.x);
    float inv1 = __builtin_amdgcn_rcpf(den.y);

    float* op = out + (size_t)(hp * 6) * NVOX + gvox;
    op[0*NVOX] = oxv.x * inv0;
    op[1*NVOX] = oyv.x * inv0;
    op[2*NVOX] = ozc.x * inv0;
    op[3*NVOX] = oxv.y * inv1;
    op[4*NVOX] = oyv.y * inv1;
    op[5*NVOX] = ozc.y * inv1;
}

extern "C" void kernel_launch(void* const* d_in, const int* in_sizes, int n_in,
                              void* d_out, int out_size, void* d_ws, size_t ws_size,
                              hipStream_t stream) {
    const float* q   = (const float*)d_in[0];
    const float* k   = (const float*)d_in[1];
    const float* rpb = (const float*)d_in[2];
    float* out = (float*)d_out;

    natt_kernel<<<500, 512, 0, stream>>>(q, k, rpb, out);
}

// Round 14
// 13.306 us; speedup vs baseline: 1.2575x; 1.0011x over previous
//
#include <hip/hip_runtime.h>

// 3D neighborhood attention, 40^3, NH=8, HD=6, KS=3 (27 neighbors).
// Tile 4x4x8 voxels x 4 head-pairs, block 512, grid 500.
// Halo 6x6x10=360 voxels staged as packed f16, one whole voxel per thread.
// T14 split staging: ALL 12 global f4 loads issued, then cvt+LDS-write.
// Interior blocks (38%) take clamp/mask-free path.
// LDS: 36 dw/voxel, hp slot 8 dw -> all 27 k-reads one base + immediates.
// s_setprio(1) around compute loop. exp2 with log2e folded into q & rpb.
// Packed f32 (v_pk_mul) for q-scale and epilogue.

#define GS   40
#define NVOX (GS*GS*GS)
#define VST  36              // dwords per halo voxel in LDS

typedef __fp16 half2_t __attribute__((ext_vector_type(2)));
typedef float  f2      __attribute__((ext_vector_type(2)));

__device__ __forceinline__ float fdot2(half2_t a, half2_t b, float c) {
    return __builtin_amdgcn_fdot2(a, b, c, false);
}
__device__ __forceinline__ half2_t h2(unsigned int u) {
    return __builtin_bit_cast(half2_t, u);
}
__device__ __forceinline__ unsigned int pk(float a, float b) {
    return __builtin_bit_cast(unsigned int, __builtin_amdgcn_cvt_pkrtz(a, b));
}

__global__ __launch_bounds__(512, 4) void natt_kernel(
    const float* __restrict__ q, const float* __restrict__ kk,
    const float* __restrict__ rpb, float* __restrict__ out)
{
    __shared__ __align__(16) unsigned int sk[360 * VST];  // 51.8 KB
    __shared__ float srpb[4 * 72];                        // [hp][9 grp][4 f2]

    int t = threadIdx.x;
    int b = blockIdx.x;
    // bijective XCD swizzle for 500 blocks (q=62, r=4); consecutive w are
    // z-adjacent tiles -> same XCD: L2 merges shared out-lines + halo faces.
    int xcd = b & 7, off = b >> 3;
    int w = (xcd < 4 ? xcd * 63 : 252 + (xcd - 4) * 62) + off;
    int bz = w % 5, byx = w / 5;
    int by = byx % 10, bx = byx / 10;
    int x0 = bx * 4, y0 = by * 4, z0 = bz * 8;

    // ---- q loads issued first (overlap staging) ----
    int hp = t & 3;
    int v  = t >> 2;                  // 0..127
    int vz = v & 7, vy = (v >> 3) & 3, vx = v >> 5;   // z=8, y=4, x=4
    int gvox = (x0 + vx) * 1600 + (y0 + vy) * 40 + (z0 + vz);
    const float4* qp = (const float4*)q + (size_t)gvox * 12 + hp * 3;
    float4 qa = qp[0], qb = qp[1], qc = qp[2];

    if (t < 216) {
        int h = t / 27, n = t - h * 27;
        int i = n / 9, r9 = n - i * 9;
        int j = r9 / 3, l = r9 - j * 3;
        srpb[(h >> 1) * 72 + ((i * 3 + j) * 4 + l) * 2 + (h & 1)] =
            rpb[t] * 1.4426950408889634f;
    }

    // ---- stage halo: one whole voxel per thread (t<360), z-major ----
    // T14 split: issue ALL 12 f4 loads, then convert+write.
    bool interior = (x0 >= 1) & (x0 <= 35) & (y0 >= 1) & (y0 <= 35) &
                    (z0 >= 1) & (z0 <= 31);
    if (t < 360) {
        int hx = t / 60, r60 = t - hx * 60;
        int hy = r60 / 10, hz = r60 - hy * 10;
        int gx = x0 + hx - 1, gy = y0 + hy - 1, gz = z0 + hz - 1;
        unsigned int* dst = sk + t * VST;
        float4 f[12];
        unsigned m;
        if (interior) {
            const float4* src = (const float4*)kk +
                                (size_t)(gx * 1600 + gy * 40 + gz) * 12;
            #pragma unroll
            for (int g = 0; g < 12; ++g) f[g] = src[g];
            m = 0xffffffffu;
        } else {
            m = (((unsigned)gx < GS) & ((unsigned)gy < GS) &
                 ((unsigned)gz < GS)) ? 0xffffffffu : 0u;
            int cx = min(max(gx, 0), GS - 1);
            int cy = min(max(gy, 0), GS - 1);
            int cz = min(max(gz, 0), GS - 1);
            const float4* src = (const float4*)kk +
                                (size_t)(cx * 1600 + cy * 40 + cz) * 12;
            #pragma unroll
            for (int g = 0; g < 12; ++g) f[g] = src[g];
        }
        #pragma unroll
        for (int hpc = 0; hpc < 4; ++hpc) {
            float4 f0 = f[hpc * 3 + 0];
            float4 f1 = f[hpc * 3 + 1];
            float4 fv = f[hpc * 3 + 2];
            uint4 u4v;
            u4v.x = pk(f0.x, f0.y) & m; u4v.y = pk(f0.z, f0.w) & m;
            u4v.z = pk(f1.x, f1.y) & m; u4v.w = pk(f1.z, f1.w) & m;
            uint2 u2v;
            u2v.x = pk(fv.x, fv.y) & m; u2v.y = pk(fv.z, fv.w) & m;
            *(uint4*)(dst + hpc * 8)     = u4v;
            *(uint2*)(dst + hpc * 8 + 4) = u2v;
        }
    }

    // ---- pack q into 6 half2, pre-scaled (packed f32 muls) ----
    const float QS = 0.4082482904638631f * 1.4426950408889634f;
    const f2 QS2 = {QS, QS};
    f2 p0 = f2{qa.x, qa.y} * QS2, p1 = f2{qa.z, qa.w} * QS2;
    f2 p2 = f2{qb.x, qb.y} * QS2, p3 = f2{qb.z, qb.w} * QS2;
    f2 p4 = f2{qc.x, qc.y} * QS2, p5 = f2{qc.z, qc.w} * QS2;
    half2_t qh0 = __builtin_amdgcn_cvt_pkrtz(p0.x, p0.y);
    half2_t qh1 = __builtin_amdgcn_cvt_pkrtz(p1.x, p1.y);
    half2_t qh2 = __builtin_amdgcn_cvt_pkrtz(p2.x, p2.y);
    half2_t qh3 = __builtin_amdgcn_cvt_pkrtz(p3.x, p3.y);
    half2_t qh4 = __builtin_amdgcn_cvt_pkrtz(p4.x, p4.y);
    half2_t qh5 = __builtin_amdgcn_cvt_pkrtz(p5.x, p5.y);

    __syncthreads();

    // ---- compute: one base reg, all 27 reads via compile-time immediates ----
    __builtin_amdgcn_s_setprio(1);
    const unsigned int* kbp = sk + ((vx * 6 + vy) * 10 + vz) * VST + hp * 8;
    const float* rbp = srpb + hp * 72;

    f2 ozc = {0,0};
    f2 xb0 = {0,0}, xb1 = {0,0}, xb2 = {0,0};
    f2 yb0 = {0,0}, yb1 = {0,0}, yb2 = {0,0};

    #pragma unroll
    for (int i = 0; i < 3; ++i)
    #pragma unroll
    for (int j = 0; j < 3; ++j) {
        const unsigned int* cb = kbp + (i * 60 + j * 10) * VST;
        float4 rp01 = *(const float4*)(rbp + (i * 3 + j) * 8);
        f2     rp2v = *(const f2*)(rbp + (i * 3 + j) * 8 + 4);
        f2 ev[3];
        #pragma unroll
        for (int l = 0; l < 3; ++l) {
            uint4 a = *(const uint4*)(cb + l * VST);
            uint2 c = *(const uint2*)(cb + l * VST + 4);
            float rx = (l == 0) ? rp01.x : (l == 1) ? rp01.z : rp2v.x;
            float ry = (l == 0) ? rp01.y : (l == 1) ? rp01.w : rp2v.y;
            float d0 = fdot2(qh0, h2(a.x),
                       fdot2(qh1, h2(a.y),
                       fdot2(qh2, h2(a.z), rx)));
            float d1 = fdot2(qh3, h2(a.w),
                       fdot2(qh4, h2(c.x),
                       fdot2(qh5, h2(c.y), ry)));
            ev[l].x = __builtin_amdgcn_exp2f(d0);
            ev[l].y = __builtin_amdgcn_exp2f(d1);
        }
        f2 A = ev[0] + ev[1] + ev[2];
        ozc += ev[2] - ev[0];
        if (i == 0)      xb0 += A;
        else if (i == 1) xb1 += A;
        else             xb2 += A;
        if (j == 0)      yb0 += A;
        else if (j == 1) yb1 += A;
        else             yb2 += A;
    }
    __builtin_amdgcn_s_setprio(0);

    f2 den = xb0 + xb1 + xb2;
    f2 oxv = xb2 - xb0, oyv = yb2 - yb0;
    f2 invv;
    invv.x = __builtin_amdgcn_rcpf(den.x);
    invv.y = __builtin_amdgcn_rcpf(den.y);
    f2 oxs = oxv * invv, oys = oyv * invv, ozs = ozc * invv;

    float* op = out + (size_t)(hp * 6) * NVOX + gvox;
    op[0*NVOX] = oxs.x;
    op[1*NVOX] = oys.x;
    op[2*NVOX] = ozs.x;
    op[3*NVOX] = oxs.y;
    op[4*NVOX] = oys.y;
    op[5*NVOX] = ozs.y;
}

extern "C" void kernel_launch(void* const* d_in, const int* in_sizes, int n_in,
                              void* d_out, int out_size, void* d_ws, size_t ws_size,
                              hipStream_t stream) {
    const float* q   = (const float*)d_in[0];
    const float* k   = (const float*)d_in[1];
    const float* rpb = (const float*)d_in[2];
    float* out = (float*)d_out;

    natt_kernel<<<500, 512, 0, stream>>>(q, k, rpb, out);
}